// Round 7
// baseline (171.974 us; speedup 1.0000x reference)
//
#include <hip/hip_runtime.h>
#include <hip/hip_bf16.h>

// WindowAttention3D: B=64 windows, N=512 tokens, H=6 heads, D=32, C=192.
// 3 launches:
//   prep_kernel: wconv (w_qkv->bf16) || cpb MLP || maskbits (float4 + nibble
//                shuffle-OR reduce; mask -> unmasked-bit words)
//   mid_kernel:  qkv bf16-MFMA GEMM || bias_expand (tab6 gather -> fp16)
//   attn_kernel: 64 q-rows/wave, swapped QK^T (mfma(K,Q)), 64-key iters;
//                per-lane POINTER-INCREMENT addressing (imm offsets);
//                bias double-buffered one iteration ahead, pinned with
//                sched_barrier(0) so the compiler cannot sink the prefetch;
//                P relayout in-register via permlane32/16_swap; exp2 no-max
//                softmax; bit-mask select.

typedef __bf16 bf16x8 __attribute__((ext_vector_type(8)));
typedef __bf16 bf16x4v __attribute__((ext_vector_type(4)));
typedef float  f32x4  __attribute__((ext_vector_type(4)));
typedef _Float16 f16x4 __attribute__((ext_vector_type(4)));
typedef unsigned uint2v __attribute__((ext_vector_type(2)));
typedef unsigned long long u64;

#define LOG2E 1.4426950408889634f

__device__ __forceinline__ bf16x8 cvt2_bf16x8(f32x4 a, f32x4 b) {
  bf16x8 r;
  r[0] = (__bf16)a[0]; r[1] = (__bf16)a[1]; r[2] = (__bf16)a[2]; r[3] = (__bf16)a[3];
  r[4] = (__bf16)b[0]; r[5] = (__bf16)b[1]; r[6] = (__bf16)b[2]; r[7] = (__bf16)b[3];
  return r;
}

__device__ __forceinline__ unsigned pack2bf(float a, float b) {
  unsigned short ua = __builtin_bit_cast(unsigned short, (__bf16)a);
  unsigned short ub = __builtin_bit_cast(unsigned short, (__bf16)b);
  return (unsigned)ua | ((unsigned)ub << 16);
}

__device__ __forceinline__ bf16x8 frag_from_words(unsigned w0, unsigned w1,
                                                  unsigned w2, unsigned w3) {
  union { unsigned u[4]; bf16x8 v; } f;
  f.u[0] = w0; f.u[1] = w1; f.u[2] = w2; f.u[3] = w3;
  return f.v;
}

// ---------------- k1: fused prep (wconv || cpb || maskbits) -----------------
#define PREP_WCONV 108
#define PREP_CPB   3375
#define PREP_WC    (PREP_WCONV + PREP_CPB)     // 3483
#define PREP_GRID  12288
#define PREP_MB    (PREP_GRID - PREP_WC)       // 8805

__global__ __launch_bounds__(256) void prep_kernel(
    const float* __restrict__ w, __bf16* __restrict__ wbf,
    const float* __restrict__ table, const float* __restrict__ w1,
    const float* __restrict__ b1, const float* __restrict__ w2,
    float* __restrict__ tab6,
    const float* __restrict__ m, u64* __restrict__ bits)
{
  __shared__ float red[4][6];
  int blk = blockIdx.x;
  if (blk < PREP_WCONV) {
    int t = blk * 256 + threadIdx.x;
    f32x4 v = *(const f32x4*)(w + (size_t)t * 4);
    bf16x4v o;
    o[0] = (__bf16)v[0]; o[1] = (__bf16)v[1]; o[2] = (__bf16)v[2]; o[3] = (__bf16)v[3];
    *(bf16x4v*)(wbf + (size_t)t * 4) = o;
  } else if (blk < PREP_WC) {
    int p = blk - PREP_WCONV;
    float c0 = table[p * 3 + 0], c1 = table[p * 3 + 1], c2 = table[p * 3 + 2];
    float acc[6] = {0.f, 0.f, 0.f, 0.f, 0.f, 0.f};
#pragma unroll
    for (int jj = 0; jj < 2; ++jj) {
      int j = threadIdx.x + jj * 256;
      float hv = w1[j * 3 + 0] * c0 + w1[j * 3 + 1] * c1 + w1[j * 3 + 2] * c2 + b1[j];
      hv = fmaxf(hv, 0.0f);
#pragma unroll
      for (int t = 0; t < 6; ++t) acc[t] += w2[t * 512 + j] * hv;
    }
#pragma unroll
    for (int t = 0; t < 6; ++t) {
      acc[t] += __shfl_xor(acc[t], 1);
      acc[t] += __shfl_xor(acc[t], 2);
      acc[t] += __shfl_xor(acc[t], 4);
      acc[t] += __shfl_xor(acc[t], 8);
      acc[t] += __shfl_xor(acc[t], 16);
      acc[t] += __shfl_xor(acc[t], 32);
    }
    int wave = threadIdx.x >> 6;
    if ((threadIdx.x & 63) == 0)
#pragma unroll
      for (int t = 0; t < 6; ++t) red[wave][t] = acc[t];
    __syncthreads();
    if (threadIdx.x < 6) {
      int t = threadIdx.x;
      float s = red[0][t] + red[1][t] + red[2][t] + red[3][t];
      float sig = 16.0f / (1.0f + expf(-s));
      tab6[p * 6 + t] = sig * LOG2E;    // pre-scale by log2e
    }
  } else {
    // maskbits, float4: thread handles 4 consecutive elems -> nibble;
    // 16-lane group ORs nibbles into one u64 word (elements 64j..64j+63).
    int lane = threadIdx.x & 63;
    int li16 = lane & 15;
    for (size_t t = (size_t)(blk - PREP_WC) * 256 + threadIdx.x;
         t < 4194304ull; t += (size_t)PREP_MB * 256) {
      f32x4 v = *(const f32x4*)(m + t * 4);
      unsigned nib = (v[0] == 0.f ? 1u : 0u) | (v[1] == 0.f ? 2u : 0u) |
                     (v[2] == 0.f ? 4u : 0u) | (v[3] == 0.f ? 8u : 0u);
      u64 part = (u64)nib << (4 * li16);
      part |= __shfl_xor(part, 1);
      part |= __shfl_xor(part, 2);
      part |= __shfl_xor(part, 4);
      part |= __shfl_xor(part, 8);
      if (li16 == 0) {
        int w_ = (int)(t >> 4);          // word index (group-base lane)
        int b = w_ >> 12, i = (w_ >> 3) & 511, jw = w_ & 7;
        bits[(((size_t)b * 8 + jw) << 9) + i] = part;
      }
    }
  }
}

// ---------------- k2: fused mid (qkv || bias_expand) ------------------------
#define MID_QKV  1024
#define MID_BIAS 1366
#define MID_GRID (MID_QKV + MID_BIAS)

__global__ __launch_bounds__(192) void mid_kernel(
    const float* __restrict__ x,       // (32768,192) fp32
    const __bf16* __restrict__ wbf,    // (576,192) bf16
    const float* __restrict__ qb,      // (192)
    const float* __restrict__ vb,      // (192)
    __bf16* __restrict__ Qo,           // (64*6,512,32)
    __bf16* __restrict__ Ko,           // (64*6,512,32)
    __bf16* __restrict__ Vt,           // (64*6,32,512)
    const int* __restrict__ relidx,    // (512,512)
    const float* __restrict__ tab6,    // (3375,6)
    _Float16* __restrict__ biasH)      // (6,512,512) fp16, pre-scaled LOG2E
{
  __shared__ __bf16 tile[2][32][72];   // per-wave private transpose staging
  if (blockIdx.x >= MID_QKV) {
    for (int ij = (blockIdx.x - MID_QKV) * 192 + threadIdx.x; ij < 262144;
         ij += MID_BIAS * 192) {
      int idx = relidx[ij];
#pragma unroll
      for (int t = 0; t < 6; ++t)
        biasH[(size_t)t * 262144 + ij] = (_Float16)tab6[idx * 6 + t];
    }
    return;
  }
  const float CQ = 0.17677669529663687f * LOG2E;  // 1/sqrt(32) * log2e
  int lane = threadIdx.x & 63, wave = threadIdx.x >> 6;
  int g = lane >> 4, li = lane & 15;
  int rowbase = blockIdx.x * 32;
  int b = rowbase >> 9, nbase = rowbase & 511;

  bf16x8 a[2][6];
#pragma unroll
  for (int mm = 0; mm < 2; ++mm)
#pragma unroll
    for (int k = 0; k < 6; ++k) {
      const float* xp = x + (size_t)(rowbase + mm * 16 + li) * 192 + k * 32 + 8 * g;
      f32x4 x0 = *(const f32x4*)xp;
      f32x4 x1 = *(const f32x4*)(xp + 4);
      a[mm][k] = cvt2_bf16x8(x0, x1);
    }

  for (int ncl = 0; ncl < 3; ++ncl) {
    int nc = wave * 3 + ncl;           // output col chunk of 64 (region=wave)
    f32x4 acc[2][4];
#pragma unroll
    for (int n = 0; n < 4; ++n) {
      int r = nc * 64 + n * 16 + li;
      float bb = 0.0f;
      if (r < 192) bb = qb[r];
      else if (r >= 384) bb = vb[r - 384];
      f32x4 v = {bb, bb, bb, bb};
      acc[0][n] = v; acc[1][n] = v;
    }
#pragma unroll
    for (int k = 0; k < 6; ++k) {
#pragma unroll
      for (int n = 0; n < 4; ++n) {
        bf16x8 bf = *(const bf16x8*)(wbf + (size_t)(nc * 64 + n * 16 + li) * 192 + k * 32 + 8 * g);
        acc[0][n] = __builtin_amdgcn_mfma_f32_16x16x32_bf16(a[0][k], bf, acc[0][n], 0, 0, 0);
        acc[1][n] = __builtin_amdgcn_mfma_f32_16x16x32_bf16(a[1][k], bf, acc[1][n], 0, 0, 0);
      }
    }
    // Epilogue. tile[wave] written+read by the SAME wave only — no barrier.
    if (wave < 2) {
      float scale = (wave == 0) ? CQ : 1.0f;
#pragma unroll
      for (int n = 0; n < 4; ++n)
#pragma unroll
        for (int mm = 0; mm < 2; ++mm)
#pragma unroll
          for (int t = 0; t < 4; ++t)
            tile[wave][mm * 16 + 4 * g + t][n * 16 + li] = (__bf16)(acc[mm][n][t] * scale);
      int tok = lane & 31, hh = lane >> 5;
      int h = (nc * 2 + hh) % 6;
      __bf16* base = (wave == 0) ? Qo : Ko;
      __bf16* dst = base + ((size_t)(b * 6 + h) * 512 + nbase + tok) * 32;
#pragma unroll
      for (int kq = 0; kq < 4; ++kq)
        *(bf16x8*)(dst + kq * 8) = *(const bf16x8*)&tile[wave][tok][hh * 32 + kq * 8];
    } else {
#pragma unroll
      for (int n = 0; n < 4; ++n) {
        int rr = nc * 64 + n * 16 + li - 384, h = rr >> 5, d = rr & 31;
#pragma unroll
        for (int mm = 0; mm < 2; ++mm) {
          int nn = nbase + mm * 16 + 4 * g;
          bf16x4v pk;
#pragma unroll
          for (int t = 0; t < 4; ++t) pk[t] = (__bf16)acc[mm][n][t];
          *(bf16x4v*)(Vt + ((size_t)(b * 6 + h) * 32 + d) * 512 + nn) = pk;
        }
      }
    }
  }
}

// ---------------- k4: attention (64 q-rows/wave, forced bias prefetch) ------
// ISSUE_LOADS: K/V/bits for iter KBN + bias for iter KBN+1 into HVN, then a
// sched_barrier(0) pins the loads above the following compute.
#define ISSUE_LOADS(HVN, KBN)                                                  \
  do {                                                                         \
    _Pragma("unroll") for (int kf = 0; kf < 4; ++kf)                           \
      kfr[kf] = *(const bf16x8*)(kp + kf * 512);                               \
    vfr[0][0] = *(const bf16x8*)(vp0);                                         \
    vfr[0][1] = *(const bf16x8*)(vp0 + 32);                                    \
    vfr[1][0] = *(const bf16x8*)(vp1);                                         \
    vfr[1][1] = *(const bf16x8*)(vp1 + 32);                                    \
    _Pragma("unroll") for (int qf = 0; qf < 4; ++qf)                           \
      mb[qf] = bitp[qf * 16] >> gsh;                                           \
    if ((KBN) < 7) {                                                           \
      _Pragma("unroll") for (int qf = 0; qf < 4; ++qf)                         \
        _Pragma("unroll") for (int kf = 0; kf < 4; ++kf)                       \
          HVN[qf][kf] = *(const f16x4*)(bq[qf] + ((KBN) + 1) * 64 + kf * 16);  \
    }                                                                          \
    __builtin_amdgcn_sched_barrier(0);                                         \
  } while (0)

#define COMPUTE_ITER(HVC)                                                      \
  do {                                                                         \
    _Pragma("unroll") for (int c = 0; c < 2; ++c) {                            \
      unsigned lo[4][2], hi[4][2];                                             \
      _Pragma("unroll") for (int kfl = 0; kfl < 2; ++kfl) {                    \
        const int kf = c * 2 + kfl;                                            \
        _Pragma("unroll") for (int qf = 0; qf < 4; ++qf) {                     \
          f16x4 hb = HVC[qf][kf];                                              \
          f32x4 ci = {(float)hb[0], (float)hb[1], (float)hb[2], (float)hb[3]}; \
          f32x4 s = __builtin_amdgcn_mfma_f32_16x16x32_bf16(kfr[kf], qfrag[qf], ci, 0, 0, 0); \
          unsigned nib = (unsigned)(mb[qf] >> (kf * 16)) & 15u;                \
          float p0 = (nib & 1u) ? __builtin_amdgcn_exp2f(s[0]) : 0.0f;         \
          float p1 = (nib & 2u) ? __builtin_amdgcn_exp2f(s[1]) : 0.0f;         \
          float p2 = (nib & 4u) ? __builtin_amdgcn_exp2f(s[2]) : 0.0f;         \
          float p3 = (nib & 8u) ? __builtin_amdgcn_exp2f(s[3]) : 0.0f;         \
          l_part[qf] += (p0 + p1) + (p2 + p3);                                 \
          lo[qf][kfl] = pack2bf(p0, p1);                                       \
          hi[qf][kfl] = pack2bf(p2, p3);                                       \
        }                                                                      \
      }                                                                        \
      _Pragma("unroll") for (int qf = 0; qf < 4; ++qf) {                       \
        uint2v sl = __builtin_amdgcn_permlane32_swap(lo[qf][0], lo[qf][1], 0, 0); \
        uint2v wl = __builtin_amdgcn_permlane16_swap(sl.x, sl.y, 0, 0);        \
        uint2v sh = __builtin_amdgcn_permlane32_swap(hi[qf][0], hi[qf][1], 0, 0); \
        uint2v wh = __builtin_amdgcn_permlane16_swap(sh.x, sh.y, 0, 0);        \
        bf16x8 pf = frag_from_words(wl.x, wh.x, wl.y, wh.y);                   \
        oacc[qf][0] = __builtin_amdgcn_mfma_f32_16x16x32_bf16(vfr[0][c], pf, oacc[qf][0], 0, 0, 0); \
        oacc[qf][1] = __builtin_amdgcn_mfma_f32_16x16x32_bf16(vfr[1][c], pf, oacc[qf][1], 0, 0, 0); \
      }                                                                        \
    }                                                                          \
  } while (0)

#define ADVANCE()                                                              \
  do { kp += 2048; vp0 += 64; vp1 += 64; bitp += 512; } while (0)

__global__ __launch_bounds__(256, 3) void attn_kernel(
    const u64* __restrict__ bits,      // (64,8,512) unmasked-bit words
    const _Float16* __restrict__ biasH,// (6,512,512) fp16, pre-scaled LOG2E
    const __bf16* __restrict__ Qw,     // (64*6,512,32), pre-scaled
    const __bf16* __restrict__ Kw,     // (64*6,512,32)
    const __bf16* __restrict__ Vt,     // (64*6,32,512)
    float* __restrict__ out)           // (64,6,512,32) fp32
{
  // 768 blocks: XCD-chunked bijective swizzle (768 % 8 == 0, 96/XCD)
  int hw = blockIdx.x;
  int wgid = (hw & 7) * 96 + (hw >> 3);
  int qt = wgid & 1, h = (wgid >> 1) % 6, b = wgid / 12;
  int lane = threadIdx.x & 63, wave = threadIdx.x >> 6;
  int g = lane >> 4, li = lane & 15;
  int qbase = qt * 256 + wave * 64;    // 64 q-rows per wave
  int bh = b * 6 + h;
  int gsh = 4 * g;

  // Per-lane base pointers; in-loop offsets are immediates, bases advance by
  // constants (ADVANCE) — minimal address VALU.
  const __bf16* kp  = Kw + (size_t)bh * 16384 + li * 32 + 8 * g;
  const __bf16* vp0 = Vt + (size_t)bh * 16384 + li * 512 + 8 * g;
  const __bf16* vp1 = vp0 + 16 * 512;
  const u64*   bitp = bits + (size_t)b * 4096 + qbase + li;
  const _Float16* bq[4];
#pragma unroll
  for (int qf = 0; qf < 4; ++qf)
    bq[qf] = biasH + (size_t)h * 262144 + (size_t)(qbase + qf * 16 + li) * 512 + gsh;

  bf16x8 qfrag[4];
#pragma unroll
  for (int qf = 0; qf < 4; ++qf)
    qfrag[qf] = *(const bf16x8*)(Qw + (size_t)bh * 16384 + (qbase + qf * 16 + li) * 32 + 8 * g);

  f32x4 oacc[4][2] = {};        // [qf][df]: O^T frags (col=i, row=d)
  float l_part[4] = {0.f, 0.f, 0.f, 0.f};
  bf16x8 kfr[4], vfr[2][2];
  u64 mb[4];
  f16x4 hvA[4][4], hvB[4][4];

  // Prologue: bias for iter 0 into hvA.
#pragma unroll
  for (int qf = 0; qf < 4; ++qf)
#pragma unroll
    for (int kf = 0; kf < 4; ++kf)
      hvA[qf][kf] = *(const f16x4*)(bq[qf] + kf * 16);

  for (int kb = 0; kb < 8; kb += 2) {
    ISSUE_LOADS(hvB, kb);        // K/V/bits for kb, bias for kb+1
    COMPUTE_ITER(hvA);
    ADVANCE();
    ISSUE_LOADS(hvA, kb + 1);    // K/V/bits for kb+1, bias for kb+2
    COMPUTE_ITER(hvB);
    ADVANCE();
  }

  // Epilogue: finish row sums across lane-groups, normalize, store f32x4.
#pragma unroll
  for (int qf = 0; qf < 4; ++qf) {
    float l = l_part[qf];
    l += __shfl_xor(l, 16);
    l += __shfl_xor(l, 32);
    float linv = 1.0f / l;
#pragma unroll
    for (int df = 0; df < 2; ++df) {
      float* op = out + ((size_t)bh * 512 + qbase + qf * 16 + li) * 32 + df * 16 + 4 * g;
      f32x4 r = oacc[qf][df] * linv;
      *(f32x4*)op = r;
    }
  }
}

extern "C" void kernel_launch(void* const* d_in, const int* in_sizes, int n_in,
                              void* d_out, int out_size, void* d_ws, size_t ws_size,
                              hipStream_t stream) {
  const float* x    = (const float*)d_in[0];
  const float* mask = (const float*)d_in[1];
  const float* wqkv = (const float*)d_in[2];
  const float* qb   = (const float*)d_in[3];
  const float* vb   = (const float*)d_in[4];
  const float* w1   = (const float*)d_in[5];
  const float* b1   = (const float*)d_in[6];
  const float* w2   = (const float*)d_in[7];
  const float* tbl  = (const float*)d_in[8];
  const int*   ridx = (const int*)d_in[9];
  float* out = (float*)d_out;

  char* ws = (char*)d_ws;
  float*    tab6  = (float*)(ws);                         //    81,920 B
  _Float16* biasH = (_Float16*)(ws + 81920);              // 3,145,728 B
  u64*      bits  = (u64*)(ws + 81920 + 3145728);         // 2,097,152 B
  __bf16*   wbf   = (__bf16*)(ws + 81920 + 3145728 + 2097152);  // pad 262,144
  __bf16*   Q     = (__bf16*)(ws + 81920 + 3145728 + 2097152 + 262144);
  __bf16*   K     = Q + (size_t)64 * 6 * 512 * 32;        // 12,582,912 B each
  __bf16*   Vt    = K + (size_t)64 * 6 * 512 * 32;
  // total ws use: ~43.3 MB

  prep_kernel<<<PREP_GRID, 256, 0, stream>>>(wqkv, wbf, tbl, w1, b1, w2, tab6,
                                             mask, bits);
  mid_kernel<<<MID_GRID, 192, 0, stream>>>(x, wbf, qb, vb, Q, K, Vt,
                                           ridx, tab6, biasH);
  attn_kernel<<<768, 256, 0, stream>>>(bits, biasH, Q, K, Vt, out);
}

// Round 8
// 136.202 us; speedup vs baseline: 1.2626x; 1.2626x over previous
//
#include <hip/hip_runtime.h>
#include <hip/hip_bf16.h>

// WindowAttention3D: B=64 windows, N=512 tokens, H=6 heads, D=32, C=192.
// 3 launches (restructured so the 67MB mask read overlaps the QKV GEMM):
//   k1 prep_kernel: wconv (w_qkv->bf16) || cpb MLP (tab6)        [tiny]
//   k2 mid_kernel:  qkv bf16-MFMA GEMM || maskbits || bias_expand
//   k3 attn_kernel: 64 q-rows/wave, swapped QK^T (mfma(K,Q)), loads batched
//                   at iter top (compiler-scheduled — forcing prefetch via
//                   sched_barrier spilled to scratch in R7, reverted);
//                   P relayout in-register via permlane32/16_swap; exp2
//                   no-max softmax; bit-mask select; XCD-chunked swizzle.

typedef __bf16 bf16x8 __attribute__((ext_vector_type(8)));
typedef __bf16 bf16x4v __attribute__((ext_vector_type(4)));
typedef float  f32x4  __attribute__((ext_vector_type(4)));
typedef _Float16 f16x4 __attribute__((ext_vector_type(4)));
typedef unsigned uint2v __attribute__((ext_vector_type(2)));
typedef unsigned long long u64;

#define LOG2E 1.4426950408889634f

__device__ __forceinline__ bf16x8 cvt2_bf16x8(f32x4 a, f32x4 b) {
  bf16x8 r;
  r[0] = (__bf16)a[0]; r[1] = (__bf16)a[1]; r[2] = (__bf16)a[2]; r[3] = (__bf16)a[3];
  r[4] = (__bf16)b[0]; r[5] = (__bf16)b[1]; r[6] = (__bf16)b[2]; r[7] = (__bf16)b[3];
  return r;
}

__device__ __forceinline__ unsigned pack2bf(float a, float b) {
  unsigned short ua = __builtin_bit_cast(unsigned short, (__bf16)a);
  unsigned short ub = __builtin_bit_cast(unsigned short, (__bf16)b);
  return (unsigned)ua | ((unsigned)ub << 16);
}

__device__ __forceinline__ bf16x8 frag_from_words(unsigned w0, unsigned w1,
                                                  unsigned w2, unsigned w3) {
  union { unsigned u[4]; bf16x8 v; } f;
  f.u[0] = w0; f.u[1] = w1; f.u[2] = w2; f.u[3] = w3;
  return f.v;
}

// ---------------- k1: prep (wconv || cpb) -----------------------------------
#define PREP_WCONV 108
#define PREP_CPB   3375
#define PREP_GRID  (PREP_WCONV + PREP_CPB)    // 3483

__global__ __launch_bounds__(256) void prep_kernel(
    const float* __restrict__ w, __bf16* __restrict__ wbf,
    const float* __restrict__ table, const float* __restrict__ w1,
    const float* __restrict__ b1, const float* __restrict__ w2,
    float* __restrict__ tab6)
{
  __shared__ float red[4][6];
  int blk = blockIdx.x;
  if (blk < PREP_WCONV) {
    int t = blk * 256 + threadIdx.x;
    f32x4 v = *(const f32x4*)(w + (size_t)t * 4);
    bf16x4v o;
    o[0] = (__bf16)v[0]; o[1] = (__bf16)v[1]; o[2] = (__bf16)v[2]; o[3] = (__bf16)v[3];
    *(bf16x4v*)(wbf + (size_t)t * 4) = o;
  } else {
    int p = blk - PREP_WCONV;
    float c0 = table[p * 3 + 0], c1 = table[p * 3 + 1], c2 = table[p * 3 + 2];
    float acc[6] = {0.f, 0.f, 0.f, 0.f, 0.f, 0.f};
#pragma unroll
    for (int jj = 0; jj < 2; ++jj) {
      int j = threadIdx.x + jj * 256;
      float hv = w1[j * 3 + 0] * c0 + w1[j * 3 + 1] * c1 + w1[j * 3 + 2] * c2 + b1[j];
      hv = fmaxf(hv, 0.0f);
#pragma unroll
      for (int t = 0; t < 6; ++t) acc[t] += w2[t * 512 + j] * hv;
    }
#pragma unroll
    for (int t = 0; t < 6; ++t) {
      acc[t] += __shfl_xor(acc[t], 1);
      acc[t] += __shfl_xor(acc[t], 2);
      acc[t] += __shfl_xor(acc[t], 4);
      acc[t] += __shfl_xor(acc[t], 8);
      acc[t] += __shfl_xor(acc[t], 16);
      acc[t] += __shfl_xor(acc[t], 32);
    }
    int wave = threadIdx.x >> 6;
    if ((threadIdx.x & 63) == 0)
#pragma unroll
      for (int t = 0; t < 6; ++t) red[wave][t] = acc[t];
    __syncthreads();
    if (threadIdx.x < 6) {
      int t = threadIdx.x;
      float s = red[0][t] + red[1][t] + red[2][t] + red[3][t];
      float sig = 16.0f / (1.0f + expf(-s));
      tab6[p * 6 + t] = sig * LOG2E;    // pre-scale by log2e
    }
  }
}

// ---------------- k2: mid (qkv || maskbits || bias_expand) ------------------
// qkv blocks first so the GEMM starts immediately; maskbits (67MB mask read)
// and bias_expand fill the remaining CUs / tail.
#define MID_QKV  1024
#define MID_MB   4096
#define MID_BIAS 1366
#define MID_GRID (MID_QKV + MID_MB + MID_BIAS)   // 6486

__global__ __launch_bounds__(192) void mid_kernel(
    const float* __restrict__ x,       // (32768,192) fp32
    const __bf16* __restrict__ wbf,    // (576,192) bf16
    const float* __restrict__ qb,      // (192)
    const float* __restrict__ vb,      // (192)
    __bf16* __restrict__ Qo,           // (64*6,512,32)
    __bf16* __restrict__ Ko,           // (64*6,512,32)
    __bf16* __restrict__ Vt,           // (64*6,32,512)
    const int* __restrict__ relidx,    // (512,512)
    const float* __restrict__ tab6,    // (3375,6)
    _Float16* __restrict__ biasH,      // (6,512,512) fp16, pre-scaled LOG2E
    const float* __restrict__ m,       // (64,512,512) mask
    u64* __restrict__ bits)            // (64,8,512) unmasked-bit words
{
  __shared__ __bf16 tile[2][32][72];   // per-wave private transpose staging
  if (blockIdx.x >= MID_QKV + MID_MB) {
    // ---- bias_expand
    for (int ij = (blockIdx.x - MID_QKV - MID_MB) * 192 + threadIdx.x;
         ij < 262144; ij += MID_BIAS * 192) {
      int idx = relidx[ij];
#pragma unroll
      for (int t = 0; t < 6; ++t)
        biasH[(size_t)t * 262144 + ij] = (_Float16)tab6[idx * 6 + t];
    }
    return;
  }
  if (blockIdx.x >= MID_QKV) {
    // ---- maskbits, float4: thread -> nibble; 16-lane group ORs into u64.
    int li16 = threadIdx.x & 15;
    for (size_t t = (size_t)(blockIdx.x - MID_QKV) * 192 + threadIdx.x;
         t < 4194304ull; t += (size_t)MID_MB * 192) {
      f32x4 v = *(const f32x4*)(m + t * 4);
      unsigned nib = (v[0] == 0.f ? 1u : 0u) | (v[1] == 0.f ? 2u : 0u) |
                     (v[2] == 0.f ? 4u : 0u) | (v[3] == 0.f ? 8u : 0u);
      u64 part = (u64)nib << (4 * li16);
      part |= __shfl_xor(part, 1);
      part |= __shfl_xor(part, 2);
      part |= __shfl_xor(part, 4);
      part |= __shfl_xor(part, 8);
      if (li16 == 0) {
        int w_ = (int)(t >> 4);          // word index (group-base lane)
        int b = w_ >> 12, i = (w_ >> 3) & 511, jw = w_ & 7;
        bits[(((size_t)b * 8 + jw) << 9) + i] = part;
      }
    }
    return;
  }
  // ---- qkv
  const float CQ = 0.17677669529663687f * LOG2E;  // 1/sqrt(32) * log2e
  int lane = threadIdx.x & 63, wave = threadIdx.x >> 6;
  int g = lane >> 4, li = lane & 15;
  int rowbase = blockIdx.x * 32;
  int b = rowbase >> 9, nbase = rowbase & 511;

  bf16x8 a[2][6];
#pragma unroll
  for (int mm = 0; mm < 2; ++mm)
#pragma unroll
    for (int k = 0; k < 6; ++k) {
      const float* xp = x + (size_t)(rowbase + mm * 16 + li) * 192 + k * 32 + 8 * g;
      f32x4 x0 = *(const f32x4*)xp;
      f32x4 x1 = *(const f32x4*)(xp + 4);
      a[mm][k] = cvt2_bf16x8(x0, x1);
    }

  for (int ncl = 0; ncl < 3; ++ncl) {
    int nc = wave * 3 + ncl;           // output col chunk of 64 (region=wave)
    f32x4 acc[2][4];
#pragma unroll
    for (int n = 0; n < 4; ++n) {
      int r = nc * 64 + n * 16 + li;
      float bb = 0.0f;
      if (r < 192) bb = qb[r];
      else if (r >= 384) bb = vb[r - 384];
      f32x4 v = {bb, bb, bb, bb};
      acc[0][n] = v; acc[1][n] = v;
    }
#pragma unroll
    for (int k = 0; k < 6; ++k) {
#pragma unroll
      for (int n = 0; n < 4; ++n) {
        bf16x8 bf = *(const bf16x8*)(wbf + (size_t)(nc * 64 + n * 16 + li) * 192 + k * 32 + 8 * g);
        acc[0][n] = __builtin_amdgcn_mfma_f32_16x16x32_bf16(a[0][k], bf, acc[0][n], 0, 0, 0);
        acc[1][n] = __builtin_amdgcn_mfma_f32_16x16x32_bf16(a[1][k], bf, acc[1][n], 0, 0, 0);
      }
    }
    // Epilogue. tile[wave] written+read by the SAME wave only — no barrier.
    if (wave < 2) {
      float scale = (wave == 0) ? CQ : 1.0f;
#pragma unroll
      for (int n = 0; n < 4; ++n)
#pragma unroll
        for (int mm = 0; mm < 2; ++mm)
#pragma unroll
          for (int t = 0; t < 4; ++t)
            tile[wave][mm * 16 + 4 * g + t][n * 16 + li] = (__bf16)(acc[mm][n][t] * scale);
      int tok = lane & 31, hh = lane >> 5;
      int h = (nc * 2 + hh) % 6;
      __bf16* base = (wave == 0) ? Qo : Ko;
      __bf16* dst = base + ((size_t)(b * 6 + h) * 512 + nbase + tok) * 32;
#pragma unroll
      for (int kq = 0; kq < 4; ++kq)
        *(bf16x8*)(dst + kq * 8) = *(const bf16x8*)&tile[wave][tok][hh * 32 + kq * 8];
    } else {
#pragma unroll
      for (int n = 0; n < 4; ++n) {
        int rr = nc * 64 + n * 16 + li - 384, h = rr >> 5, d = rr & 31;
#pragma unroll
        for (int mm = 0; mm < 2; ++mm) {
          int nn = nbase + mm * 16 + 4 * g;
          bf16x4v pk;
#pragma unroll
          for (int t = 0; t < 4; ++t) pk[t] = (__bf16)acc[mm][n][t];
          *(bf16x4v*)(Vt + ((size_t)(b * 6 + h) * 32 + d) * 512 + nn) = pk;
        }
      }
    }
  }
}

// ---------------- k3: attention (64 q-rows/wave, round-5 structure) ---------
__global__ __launch_bounds__(256, 3) void attn_kernel(
    const u64* __restrict__ bits,      // (64,8,512) unmasked-bit words
    const _Float16* __restrict__ biasH,// (6,512,512) fp16, pre-scaled LOG2E
    const __bf16* __restrict__ Qw,     // (64*6,512,32), pre-scaled
    const __bf16* __restrict__ Kw,     // (64*6,512,32)
    const __bf16* __restrict__ Vt,     // (64*6,32,512)
    float* __restrict__ out)           // (64,6,512,32) fp32
{
  // 768 blocks: XCD-chunked bijective swizzle (768 % 8 == 0, 96/XCD)
  int hw = blockIdx.x;
  int wgid = (hw & 7) * 96 + (hw >> 3);
  int qt = wgid & 1, h = (wgid >> 1) % 6, b = wgid / 12;
  int lane = threadIdx.x & 63, wave = threadIdx.x >> 6;
  int g = lane >> 4, li = lane & 15;
  int qbase = qt * 256 + wave * 64;    // 64 q-rows per wave
  int bh = b * 6 + h;
  int gsh = 4 * g;

  const __bf16* Qb = Qw + (size_t)bh * 16384;
  const __bf16* Kb = Kw + (size_t)bh * 16384;
  const __bf16* Vb = Vt + (size_t)bh * 16384;
  const _Float16* biasb = biasH + (size_t)h * 262144;
  const u64* bitsb = bits + (size_t)b * 4096;

  bf16x8 qfrag[4];
#pragma unroll
  for (int qf = 0; qf < 4; ++qf)
    qfrag[qf] = *(const bf16x8*)(Qb + (qbase + qf * 16 + li) * 32 + 8 * g);

  f32x4 oacc[4][2] = {};        // [qf][df]: O^T frags (col=i, row=d)
  float l_part[4] = {0.f, 0.f, 0.f, 0.f};

  for (int kb = 0; kb < 8; ++kb) {      // 64 keys per iteration
    int j64 = kb * 64;
    u64 mb[4];
#pragma unroll
    for (int qf = 0; qf < 4; ++qf)
      mb[qf] = bitsb[(kb << 9) + qbase + qf * 16 + li] >> gsh;
    bf16x8 kfr[4];
#pragma unroll
    for (int kf = 0; kf < 4; ++kf)
      kfr[kf] = *(const bf16x8*)(Kb + (j64 + kf * 16 + li) * 32 + 8 * g);
    bf16x8 vfr[2][2];
#pragma unroll
    for (int df = 0; df < 2; ++df)
#pragma unroll
      for (int c = 0; c < 2; ++c)
        vfr[df][c] = *(const bf16x8*)(Vb + (df * 16 + li) * 512 + j64 + c * 32 + 8 * g);

#pragma unroll
    for (int c = 0; c < 2; ++c) {
      unsigned lo[4][2], hi[4][2];      // [qf][kfl]
#pragma unroll
      for (int kfl = 0; kfl < 2; ++kfl) {
        int kf = c * 2 + kfl;
        int j0 = j64 + kf * 16 + gsh;   // 4 consecutive keys per lane
#pragma unroll
        for (int qf = 0; qf < 4; ++qf) {
          f16x4 hb = *(const f16x4*)(biasb + (qbase + qf * 16 + li) * 512 + j0);
          f32x4 ci = {(float)hb[0], (float)hb[1], (float)hb[2], (float)hb[3]};
          f32x4 s = __builtin_amdgcn_mfma_f32_16x16x32_bf16(kfr[kf], qfrag[qf], ci, 0, 0, 0);
          unsigned nib = (unsigned)(mb[qf] >> (kf * 16)) & 15u;   // const shift
          float p0 = (nib & 1u) ? __builtin_amdgcn_exp2f(s[0]) : 0.0f;
          float p1 = (nib & 2u) ? __builtin_amdgcn_exp2f(s[1]) : 0.0f;
          float p2 = (nib & 4u) ? __builtin_amdgcn_exp2f(s[2]) : 0.0f;
          float p3 = (nib & 8u) ? __builtin_amdgcn_exp2f(s[3]) : 0.0f;
          l_part[qf] += (p0 + p1) + (p2 + p3);
          lo[qf][kfl] = pack2bf(p0, p1);
          hi[qf][kfl] = pack2bf(p2, p3);
        }
      }
      // In-register P^T relayout via permlane32_swap + permlane16_swap:
      //   {W(e0e1), W(e4e5)} = swap16(swap32(lo0, lo1))
      //   {W(e2e3), W(e6e7)} = swap16(swap32(hi0, hi1))
#pragma unroll
      for (int qf = 0; qf < 4; ++qf) {
        uint2v sl = __builtin_amdgcn_permlane32_swap(lo[qf][0], lo[qf][1], 0, 0);
        uint2v wl = __builtin_amdgcn_permlane16_swap(sl.x, sl.y, 0, 0);
        uint2v sh = __builtin_amdgcn_permlane32_swap(hi[qf][0], hi[qf][1], 0, 0);
        uint2v wh = __builtin_amdgcn_permlane16_swap(sh.x, sh.y, 0, 0);
        bf16x8 pf = frag_from_words(wl.x, wh.x, wl.y, wh.y);
#pragma unroll
        for (int df = 0; df < 2; ++df)
          oacc[qf][df] = __builtin_amdgcn_mfma_f32_16x16x32_bf16(vfr[df][c], pf, oacc[qf][df], 0, 0, 0);
      }
    }
  }

  // Epilogue: finish row sums across lane-groups, normalize, store f32x4.
#pragma unroll
  for (int qf = 0; qf < 4; ++qf) {
    float l = l_part[qf];
    l += __shfl_xor(l, 16);
    l += __shfl_xor(l, 32);
    float linv = 1.0f / l;
#pragma unroll
    for (int df = 0; df < 2; ++df) {
      float* op = out + ((size_t)bh * 512 + qbase + qf * 16 + li) * 32 + df * 16 + 4 * g;
      f32x4 r = oacc[qf][df] * linv;
      *(f32x4*)op = r;
    }
  }
}

extern "C" void kernel_launch(void* const* d_in, const int* in_sizes, int n_in,
                              void* d_out, int out_size, void* d_ws, size_t ws_size,
                              hipStream_t stream) {
  const float* x    = (const float*)d_in[0];
  const float* mask = (const float*)d_in[1];
  const float* wqkv = (const float*)d_in[2];
  const float* qb   = (const float*)d_in[3];
  const float* vb   = (const float*)d_in[4];
  const float* w1   = (const float*)d_in[5];
  const float* b1   = (const float*)d_in[6];
  const float* w2   = (const float*)d_in[7];
  const float* tbl  = (const float*)d_in[8];
  const int*   ridx = (const int*)d_in[9];
  float* out = (float*)d_out;

  char* ws = (char*)d_ws;
  float*    tab6  = (float*)(ws);                         //    81,920 B
  _Float16* biasH = (_Float16*)(ws + 81920);              // 3,145,728 B
  u64*      bits  = (u64*)(ws + 81920 + 3145728);         // 2,097,152 B
  __bf16*   wbf   = (__bf16*)(ws + 81920 + 3145728 + 2097152);  // pad 262,144
  __bf16*   Q     = (__bf16*)(ws + 81920 + 3145728 + 2097152 + 262144);
  __bf16*   K     = Q + (size_t)64 * 6 * 512 * 32;        // 12,582,912 B each
  __bf16*   Vt    = K + (size_t)64 * 6 * 512 * 32;
  // total ws use: ~43.3 MB

  prep_kernel<<<PREP_GRID, 256, 0, stream>>>(wqkv, wbf, tbl, w1, b1, w2, tab6);
  mid_kernel<<<MID_GRID, 192, 0, stream>>>(x, wbf, qb, vb, Q, K, Vt,
                                           ridx, tab6, biasH, mask, bits);
  attn_kernel<<<768, 256, 0, stream>>>(bits, biasH, Q, K, Vt, out);
}

// Round 9
// 121.677 us; speedup vs baseline: 1.4134x; 1.1194x over previous
//
#include <hip/hip_runtime.h>
#include <hip/hip_bf16.h>

// WindowAttention3D: B=64 windows, N=512 tokens, H=6 heads, D=32, C=192.
// 3 launches:
//   k1 prep_kernel: wconv (w_qkv->bf16) || cpb MLP (tab6)        [tiny]
//   k2 mid_kernel:  qkv bf16-MFMA GEMM || maskbits || bias_expand
//                   bias_expand writes biasH PERMUTED per 64-col block:
//                   position p = g*16 + kf*4 + t  <- source j = kf*16+g*4+t,
//                   so attn reads a lane's whole-iteration bias as one
//                   contiguous 32B region (2x f16x8) instead of 4x f16x4.
//   k3 attn_kernel: 64 q-rows/wave, swapped QK^T (mfma(K,Q)); bias requests
//                   halved via repack; P relayout in-register via
//                   permlane32/16_swap; exp2 no-max softmax; bit-mask select.

typedef __bf16 bf16x8 __attribute__((ext_vector_type(8)));
typedef __bf16 bf16x4v __attribute__((ext_vector_type(4)));
typedef float  f32x4  __attribute__((ext_vector_type(4)));
typedef _Float16 f16x4 __attribute__((ext_vector_type(4)));
typedef _Float16 f16x8 __attribute__((ext_vector_type(8)));
typedef unsigned uint2v __attribute__((ext_vector_type(2)));
typedef unsigned long long u64;

#define LOG2E 1.4426950408889634f

__device__ __forceinline__ bf16x8 cvt2_bf16x8(f32x4 a, f32x4 b) {
  bf16x8 r;
  r[0] = (__bf16)a[0]; r[1] = (__bf16)a[1]; r[2] = (__bf16)a[2]; r[3] = (__bf16)a[3];
  r[4] = (__bf16)b[0]; r[5] = (__bf16)b[1]; r[6] = (__bf16)b[2]; r[7] = (__bf16)b[3];
  return r;
}

__device__ __forceinline__ unsigned pack2bf(float a, float b) {
  unsigned short ua = __builtin_bit_cast(unsigned short, (__bf16)a);
  unsigned short ub = __builtin_bit_cast(unsigned short, (__bf16)b);
  return (unsigned)ua | ((unsigned)ub << 16);
}

__device__ __forceinline__ bf16x8 frag_from_words(unsigned w0, unsigned w1,
                                                  unsigned w2, unsigned w3) {
  union { unsigned u[4]; bf16x8 v; } f;
  f.u[0] = w0; f.u[1] = w1; f.u[2] = w2; f.u[3] = w3;
  return f.v;
}

// ---------------- k1: prep (wconv || cpb) -----------------------------------
#define PREP_WCONV 108
#define PREP_CPB   3375
#define PREP_GRID  (PREP_WCONV + PREP_CPB)    // 3483

__global__ __launch_bounds__(256) void prep_kernel(
    const float* __restrict__ w, __bf16* __restrict__ wbf,
    const float* __restrict__ table, const float* __restrict__ w1,
    const float* __restrict__ b1, const float* __restrict__ w2,
    float* __restrict__ tab6)
{
  __shared__ float red[4][6];
  int blk = blockIdx.x;
  if (blk < PREP_WCONV) {
    int t = blk * 256 + threadIdx.x;
    f32x4 v = *(const f32x4*)(w + (size_t)t * 4);
    bf16x4v o;
    o[0] = (__bf16)v[0]; o[1] = (__bf16)v[1]; o[2] = (__bf16)v[2]; o[3] = (__bf16)v[3];
    *(bf16x4v*)(wbf + (size_t)t * 4) = o;
  } else {
    int p = blk - PREP_WCONV;
    float c0 = table[p * 3 + 0], c1 = table[p * 3 + 1], c2 = table[p * 3 + 2];
    float acc[6] = {0.f, 0.f, 0.f, 0.f, 0.f, 0.f};
#pragma unroll
    for (int jj = 0; jj < 2; ++jj) {
      int j = threadIdx.x + jj * 256;
      float hv = w1[j * 3 + 0] * c0 + w1[j * 3 + 1] * c1 + w1[j * 3 + 2] * c2 + b1[j];
      hv = fmaxf(hv, 0.0f);
#pragma unroll
      for (int t = 0; t < 6; ++t) acc[t] += w2[t * 512 + j] * hv;
    }
#pragma unroll
    for (int t = 0; t < 6; ++t) {
      acc[t] += __shfl_xor(acc[t], 1);
      acc[t] += __shfl_xor(acc[t], 2);
      acc[t] += __shfl_xor(acc[t], 4);
      acc[t] += __shfl_xor(acc[t], 8);
      acc[t] += __shfl_xor(acc[t], 16);
      acc[t] += __shfl_xor(acc[t], 32);
    }
    int wave = threadIdx.x >> 6;
    if ((threadIdx.x & 63) == 0)
#pragma unroll
      for (int t = 0; t < 6; ++t) red[wave][t] = acc[t];
    __syncthreads();
    if (threadIdx.x < 6) {
      int t = threadIdx.x;
      float s = red[0][t] + red[1][t] + red[2][t] + red[3][t];
      float sig = 16.0f / (1.0f + expf(-s));
      tab6[p * 6 + t] = sig * LOG2E;    // pre-scale by log2e
    }
  }
}

// ---------------- k2: mid (qkv || maskbits || bias_expand) ------------------
#define MID_QKV  1024
#define MID_MB   4096
#define MID_BIAS 1366
#define MID_GRID (MID_QKV + MID_MB + MID_BIAS)   // 6486

__global__ __launch_bounds__(192) void mid_kernel(
    const float* __restrict__ x,       // (32768,192) fp32
    const __bf16* __restrict__ wbf,    // (576,192) bf16
    const float* __restrict__ qb,      // (192)
    const float* __restrict__ vb,      // (192)
    __bf16* __restrict__ Qo,           // (64*6,512,32)
    __bf16* __restrict__ Ko,           // (64*6,512,32)
    __bf16* __restrict__ Vt,           // (64*6,32,512)
    const int* __restrict__ relidx,    // (512,512)
    const float* __restrict__ tab6,    // (3375,6)
    _Float16* __restrict__ biasH,      // (6,512,512) fp16, PERMUTED, *LOG2E
    const float* __restrict__ m,       // (64,512,512) mask
    u64* __restrict__ bits)            // (64,8,512) unmasked-bit words
{
  __shared__ __bf16 tile[2][32][72];   // per-wave private transpose staging
  if (blockIdx.x >= MID_QKV + MID_MB) {
    // ---- bias_expand (permuted within each 64-col block):
    // output pos p (0..511) of row i <- source col j:
    //   jblk=p/64, g=(p%64)/16, kf=(p%16)/4, t=p%4; j = jblk*64+kf*16+g*4+t
    for (int ij = (blockIdx.x - MID_QKV - MID_MB) * 192 + threadIdx.x;
         ij < 262144; ij += MID_BIAS * 192) {
      int i = ij >> 9, p = ij & 511;
      int jblk = p >> 6, g = (p >> 4) & 3, kf = (p >> 2) & 3, t = p & 3;
      int j = (jblk << 6) + kf * 16 + g * 4 + t;
      int idx = relidx[(i << 9) + j];
#pragma unroll
      for (int t6 = 0; t6 < 6; ++t6)
        biasH[(size_t)t6 * 262144 + ij] = (_Float16)tab6[idx * 6 + t6];
    }
    return;
  }
  if (blockIdx.x >= MID_QKV) {
    // ---- maskbits, float4: thread -> nibble; 16-lane group ORs into u64.
    int li16 = threadIdx.x & 15;
    for (size_t t = (size_t)(blockIdx.x - MID_QKV) * 192 + threadIdx.x;
         t < 4194304ull; t += (size_t)MID_MB * 192) {
      f32x4 v = *(const f32x4*)(m + t * 4);
      unsigned nib = (v[0] == 0.f ? 1u : 0u) | (v[1] == 0.f ? 2u : 0u) |
                     (v[2] == 0.f ? 4u : 0u) | (v[3] == 0.f ? 8u : 0u);
      u64 part = (u64)nib << (4 * li16);
      part |= __shfl_xor(part, 1);
      part |= __shfl_xor(part, 2);
      part |= __shfl_xor(part, 4);
      part |= __shfl_xor(part, 8);
      if (li16 == 0) {
        int w_ = (int)(t >> 4);          // word index (group-base lane)
        int b = w_ >> 12, i = (w_ >> 3) & 511, jw = w_ & 7;
        bits[(((size_t)b * 8 + jw) << 9) + i] = part;
      }
    }
    return;
  }
  // ---- qkv
  const float CQ = 0.17677669529663687f * LOG2E;  // 1/sqrt(32) * log2e
  int lane = threadIdx.x & 63, wave = threadIdx.x >> 6;
  int g = lane >> 4, li = lane & 15;
  int rowbase = blockIdx.x * 32;
  int b = rowbase >> 9, nbase = rowbase & 511;

  bf16x8 a[2][6];
#pragma unroll
  for (int mm = 0; mm < 2; ++mm)
#pragma unroll
    for (int k = 0; k < 6; ++k) {
      const float* xp = x + (size_t)(rowbase + mm * 16 + li) * 192 + k * 32 + 8 * g;
      f32x4 x0 = *(const f32x4*)xp;
      f32x4 x1 = *(const f32x4*)(xp + 4);
      a[mm][k] = cvt2_bf16x8(x0, x1);
    }

  for (int ncl = 0; ncl < 3; ++ncl) {
    int nc = wave * 3 + ncl;           // output col chunk of 64 (region=wave)
    f32x4 acc[2][4];
#pragma unroll
    for (int n = 0; n < 4; ++n) {
      int r = nc * 64 + n * 16 + li;
      float bb = 0.0f;
      if (r < 192) bb = qb[r];
      else if (r >= 384) bb = vb[r - 384];
      f32x4 v = {bb, bb, bb, bb};
      acc[0][n] = v; acc[1][n] = v;
    }
#pragma unroll
    for (int k = 0; k < 6; ++k) {
#pragma unroll
      for (int n = 0; n < 4; ++n) {
        bf16x8 bf = *(const bf16x8*)(wbf + (size_t)(nc * 64 + n * 16 + li) * 192 + k * 32 + 8 * g);
        acc[0][n] = __builtin_amdgcn_mfma_f32_16x16x32_bf16(a[0][k], bf, acc[0][n], 0, 0, 0);
        acc[1][n] = __builtin_amdgcn_mfma_f32_16x16x32_bf16(a[1][k], bf, acc[1][n], 0, 0, 0);
      }
    }
    // Epilogue. tile[wave] written+read by the SAME wave only — no barrier.
    if (wave < 2) {
      float scale = (wave == 0) ? CQ : 1.0f;
#pragma unroll
      for (int n = 0; n < 4; ++n)
#pragma unroll
        for (int mm = 0; mm < 2; ++mm)
#pragma unroll
          for (int t = 0; t < 4; ++t)
            tile[wave][mm * 16 + 4 * g + t][n * 16 + li] = (__bf16)(acc[mm][n][t] * scale);
      int tok = lane & 31, hh = lane >> 5;
      int h = (nc * 2 + hh) % 6;
      __bf16* base = (wave == 0) ? Qo : Ko;
      __bf16* dst = base + ((size_t)(b * 6 + h) * 512 + nbase + tok) * 32;
#pragma unroll
      for (int kq = 0; kq < 4; ++kq)
        *(bf16x8*)(dst + kq * 8) = *(const bf16x8*)&tile[wave][tok][hh * 32 + kq * 8];
    } else {
#pragma unroll
      for (int n = 0; n < 4; ++n) {
        int rr = nc * 64 + n * 16 + li - 384, h = rr >> 5, d = rr & 31;
#pragma unroll
        for (int mm = 0; mm < 2; ++mm) {
          int nn = nbase + mm * 16 + 4 * g;
          bf16x4v pk;
#pragma unroll
          for (int t = 0; t < 4; ++t) pk[t] = (__bf16)acc[mm][n][t];
          *(bf16x4v*)(Vt + ((size_t)(b * 6 + h) * 32 + d) * 512 + nn) = pk;
        }
      }
    }
  }
}

// ---------------- k3: attention (64 q-rows/wave, repacked bias) -------------
__global__ __launch_bounds__(256, 3) void attn_kernel(
    const u64* __restrict__ bits,      // (64,8,512) unmasked-bit words
    const _Float16* __restrict__ biasH,// (6,512,512) fp16, PERMUTED, *LOG2E
    const __bf16* __restrict__ Qw,     // (64*6,512,32), pre-scaled
    const __bf16* __restrict__ Kw,     // (64*6,512,32)
    const __bf16* __restrict__ Vt,     // (64*6,32,512)
    float* __restrict__ out)           // (64,6,512,32) fp32
{
  // 768 blocks: XCD-chunked bijective swizzle (768 % 8 == 0, 96/XCD)
  int hw = blockIdx.x;
  int wgid = (hw & 7) * 96 + (hw >> 3);
  int qt = wgid & 1, h = (wgid >> 1) % 6, b = wgid / 12;
  int lane = threadIdx.x & 63, wave = threadIdx.x >> 6;
  int g = lane >> 4, li = lane & 15;
  int qbase = qt * 256 + wave * 64;    // 64 q-rows per wave
  int bh = b * 6 + h;
  int gsh = 4 * g;

  const __bf16* Qb = Qw + (size_t)bh * 16384;
  const __bf16* Kb = Kw + (size_t)bh * 16384;
  const __bf16* Vb = Vt + (size_t)bh * 16384;
  const _Float16* biasb = biasH + (size_t)h * 262144 + g * 16;
  const u64* bitsb = bits + (size_t)b * 4096;

  bf16x8 qfrag[4];
#pragma unroll
  for (int qf = 0; qf < 4; ++qf)
    qfrag[qf] = *(const bf16x8*)(Qb + (qbase + qf * 16 + li) * 32 + 8 * g);

  f32x4 oacc[4][2] = {};        // [qf][df]: O^T frags (col=i, row=d)
  float l_part[4] = {0.f, 0.f, 0.f, 0.f};

  for (int kb = 0; kb < 8; ++kb) {      // 64 keys per iteration
    int j64 = kb * 64;
    u64 mb[4];
#pragma unroll
    for (int qf = 0; qf < 4; ++qf)
      mb[qf] = bitsb[(kb << 9) + qbase + qf * 16 + li] >> gsh;
    bf16x8 kfr[4];
#pragma unroll
    for (int kf = 0; kf < 4; ++kf)
      kfr[kf] = *(const bf16x8*)(Kb + (j64 + kf * 16 + li) * 32 + 8 * g);
    bf16x8 vfr[2][2];
#pragma unroll
    for (int df = 0; df < 2; ++df)
#pragma unroll
      for (int c = 0; c < 2; ++c)
        vfr[df][c] = *(const bf16x8*)(Vb + (df * 16 + li) * 512 + j64 + c * 32 + 8 * g);
    // Repacked bias: lane's whole-iteration bias = 32B contiguous -> 2 loads.
    f16x8 hv8[4][2];
#pragma unroll
    for (int qf = 0; qf < 4; ++qf) {
      const _Float16* bp = biasb + (size_t)(qbase + qf * 16 + li) * 512 + j64;
      hv8[qf][0] = *(const f16x8*)(bp);       // kf0 (elems 0-3), kf1 (4-7)
      hv8[qf][1] = *(const f16x8*)(bp + 8);   // kf2, kf3
    }

#pragma unroll
    for (int c = 0; c < 2; ++c) {
      unsigned lo[4][2], hi[4][2];      // [qf][kfl]
#pragma unroll
      for (int kfl = 0; kfl < 2; ++kfl) {
        int kf = c * 2 + kfl;
        const int hsel = kf >> 1, hoff = (kf & 1) * 4;
#pragma unroll
        for (int qf = 0; qf < 4; ++qf) {
          f16x8 hb = hv8[qf][hsel];
          f32x4 ci = {(float)hb[hoff], (float)hb[hoff + 1],
                      (float)hb[hoff + 2], (float)hb[hoff + 3]};
          f32x4 s = __builtin_amdgcn_mfma_f32_16x16x32_bf16(kfr[kf], qfrag[qf], ci, 0, 0, 0);
          unsigned nib = (unsigned)(mb[qf] >> (kf * 16)) & 15u;   // const shift
          float p0 = (nib & 1u) ? __builtin_amdgcn_exp2f(s[0]) : 0.0f;
          float p1 = (nib & 2u) ? __builtin_amdgcn_exp2f(s[1]) : 0.0f;
          float p2 = (nib & 4u) ? __builtin_amdgcn_exp2f(s[2]) : 0.0f;
          float p3 = (nib & 8u) ? __builtin_amdgcn_exp2f(s[3]) : 0.0f;
          l_part[qf] += (p0 + p1) + (p2 + p3);
          lo[qf][kfl] = pack2bf(p0, p1);
          hi[qf][kfl] = pack2bf(p2, p3);
        }
      }
      // In-register P^T relayout via permlane32_swap + permlane16_swap:
      //   {W(e0e1), W(e4e5)} = swap16(swap32(lo0, lo1))
      //   {W(e2e3), W(e6e7)} = swap16(swap32(hi0, hi1))
#pragma unroll
      for (int qf = 0; qf < 4; ++qf) {
        uint2v sl = __builtin_amdgcn_permlane32_swap(lo[qf][0], lo[qf][1], 0, 0);
        uint2v wl = __builtin_amdgcn_permlane16_swap(sl.x, sl.y, 0, 0);
        uint2v sh = __builtin_amdgcn_permlane32_swap(hi[qf][0], hi[qf][1], 0, 0);
        uint2v wh = __builtin_amdgcn_permlane16_swap(sh.x, sh.y, 0, 0);
        bf16x8 pf = frag_from_words(wl.x, wh.x, wl.y, wh.y);
#pragma unroll
        for (int df = 0; df < 2; ++df)
          oacc[qf][df] = __builtin_amdgcn_mfma_f32_16x16x32_bf16(vfr[df][c], pf, oacc[qf][df], 0, 0, 0);
      }
    }
  }

  // Epilogue: finish row sums across lane-groups, normalize, store f32x4.
#pragma unroll
  for (int qf = 0; qf < 4; ++qf) {
    float l = l_part[qf];
    l += __shfl_xor(l, 16);
    l += __shfl_xor(l, 32);
    float linv = 1.0f / l;
#pragma unroll
    for (int df = 0; df < 2; ++df) {
      float* op = out + ((size_t)bh * 512 + qbase + qf * 16 + li) * 32 + df * 16 + 4 * g;
      f32x4 r = oacc[qf][df] * linv;
      *(f32x4*)op = r;
    }
  }
}

extern "C" void kernel_launch(void* const* d_in, const int* in_sizes, int n_in,
                              void* d_out, int out_size, void* d_ws, size_t ws_size,
                              hipStream_t stream) {
  const float* x    = (const float*)d_in[0];
  const float* mask = (const float*)d_in[1];
  const float* wqkv = (const float*)d_in[2];
  const float* qb   = (const float*)d_in[3];
  const float* vb   = (const float*)d_in[4];
  const float* w1   = (const float*)d_in[5];
  const float* b1   = (const float*)d_in[6];
  const float* w2   = (const float*)d_in[7];
  const float* tbl  = (const float*)d_in[8];
  const int*   ridx = (const int*)d_in[9];
  float* out = (float*)d_out;

  char* ws = (char*)d_ws;
  float*    tab6  = (float*)(ws);                         //    81,920 B
  _Float16* biasH = (_Float16*)(ws + 81920);              // 3,145,728 B
  u64*      bits  = (u64*)(ws + 81920 + 3145728);         // 2,097,152 B
  __bf16*   wbf   = (__bf16*)(ws + 81920 + 3145728 + 2097152);  // pad 262,144
  __bf16*   Q     = (__bf16*)(ws + 81920 + 3145728 + 2097152 + 262144);
  __bf16*   K     = Q + (size_t)64 * 6 * 512 * 32;        // 12,582,912 B each
  __bf16*   Vt    = K + (size_t)64 * 6 * 512 * 32;
  // total ws use: ~43.3 MB

  prep_kernel<<<PREP_GRID, 256, 0, stream>>>(wqkv, wbf, tbl, w1, b1, w2, tab6);
  mid_kernel<<<MID_GRID, 192, 0, stream>>>(x, wbf, qb, vb, Q, K, Vt,
                                           ridx, tab6, biasH, mask, bits);
  attn_kernel<<<768, 256, 0, stream>>>(bits, biasH, Q, K, Vt, out);
}

// Round 10
// 118.148 us; speedup vs baseline: 1.4556x; 1.0299x over previous
//
#include <hip/hip_runtime.h>
#include <hip/hip_bf16.h>

// WindowAttention3D: B=64 windows, N=512 tokens, H=6 heads, D=32, C=192.
// 3 launches:
//   k1 prep_kernel: wconv (w_qkv->bf16) || cpb MLP (tab6, padded 8/row) ||
//                   maskbits (8 elems/thread, byte + 3-level shfl-OR)
//   k2 mid_kernel:  qkv bf16-MFMA GEMM || bias_expand (x4 vectorized gather,
//                   PERMUTED per 64-col block: p = g*16+kf*4+t <- j)
//   k3 attn_kernel: 64 q-rows/wave, swapped QK^T (mfma(K,Q)); bias as 2x
//                   f16x8/iter; P relayout via permlane32/16_swap; exp2
//                   no-max softmax; bit-mask select; XCD-chunked swizzle.

typedef __bf16 bf16x8 __attribute__((ext_vector_type(8)));
typedef __bf16 bf16x4v __attribute__((ext_vector_type(4)));
typedef float  f32x4  __attribute__((ext_vector_type(4)));
typedef _Float16 f16x4 __attribute__((ext_vector_type(4)));
typedef _Float16 f16x8 __attribute__((ext_vector_type(8)));
typedef unsigned uint2v __attribute__((ext_vector_type(2)));
typedef int int4v __attribute__((ext_vector_type(4)));
typedef unsigned long long u64;

#define LOG2E 1.4426950408889634f

__device__ __forceinline__ bf16x8 cvt2_bf16x8(f32x4 a, f32x4 b) {
  bf16x8 r;
  r[0] = (__bf16)a[0]; r[1] = (__bf16)a[1]; r[2] = (__bf16)a[2]; r[3] = (__bf16)a[3];
  r[4] = (__bf16)b[0]; r[5] = (__bf16)b[1]; r[6] = (__bf16)b[2]; r[7] = (__bf16)b[3];
  return r;
}

__device__ __forceinline__ unsigned pack2bf(float a, float b) {
  unsigned short ua = __builtin_bit_cast(unsigned short, (__bf16)a);
  unsigned short ub = __builtin_bit_cast(unsigned short, (__bf16)b);
  return (unsigned)ua | ((unsigned)ub << 16);
}

__device__ __forceinline__ bf16x8 frag_from_words(unsigned w0, unsigned w1,
                                                  unsigned w2, unsigned w3) {
  union { unsigned u[4]; bf16x8 v; } f;
  f.u[0] = w0; f.u[1] = w1; f.u[2] = w2; f.u[3] = w3;
  return f.v;
}

// ---------------- k1: prep (wconv || cpb || maskbits) -----------------------
#define PREP_WCONV 108
#define PREP_CPB   3375
#define PREP_WC    (PREP_WCONV + PREP_CPB)     // 3483
#define PREP_MB    2048
#define PREP_GRID  (PREP_WC + PREP_MB)         // 5531

__global__ __launch_bounds__(256) void prep_kernel(
    const float* __restrict__ w, __bf16* __restrict__ wbf,
    const float* __restrict__ table, const float* __restrict__ w1,
    const float* __restrict__ b1, const float* __restrict__ w2,
    float* __restrict__ tab6,          // (3375,8) padded rows
    const float* __restrict__ m, u64* __restrict__ bits)
{
  __shared__ float red[4][6];
  int blk = blockIdx.x;
  if (blk < PREP_WCONV) {
    int t = blk * 256 + threadIdx.x;
    f32x4 v = *(const f32x4*)(w + (size_t)t * 4);
    bf16x4v o;
    o[0] = (__bf16)v[0]; o[1] = (__bf16)v[1]; o[2] = (__bf16)v[2]; o[3] = (__bf16)v[3];
    *(bf16x4v*)(wbf + (size_t)t * 4) = o;
  } else if (blk < PREP_WC) {
    int p = blk - PREP_WCONV;
    float c0 = table[p * 3 + 0], c1 = table[p * 3 + 1], c2 = table[p * 3 + 2];
    float acc[6] = {0.f, 0.f, 0.f, 0.f, 0.f, 0.f};
#pragma unroll
    for (int jj = 0; jj < 2; ++jj) {
      int j = threadIdx.x + jj * 256;
      float hv = w1[j * 3 + 0] * c0 + w1[j * 3 + 1] * c1 + w1[j * 3 + 2] * c2 + b1[j];
      hv = fmaxf(hv, 0.0f);
#pragma unroll
      for (int t = 0; t < 6; ++t) acc[t] += w2[t * 512 + j] * hv;
    }
#pragma unroll
    for (int t = 0; t < 6; ++t) {
      acc[t] += __shfl_xor(acc[t], 1);
      acc[t] += __shfl_xor(acc[t], 2);
      acc[t] += __shfl_xor(acc[t], 4);
      acc[t] += __shfl_xor(acc[t], 8);
      acc[t] += __shfl_xor(acc[t], 16);
      acc[t] += __shfl_xor(acc[t], 32);
    }
    int wave = threadIdx.x >> 6;
    if ((threadIdx.x & 63) == 0)
#pragma unroll
      for (int t = 0; t < 6; ++t) red[wave][t] = acc[t];
    __syncthreads();
    if (threadIdx.x < 6) {
      int t = threadIdx.x;
      float s = red[0][t] + red[1][t] + red[2][t] + red[3][t];
      float sig = 16.0f / (1.0f + expf(-s));
      tab6[p * 8 + t] = sig * LOG2E;    // pre-scale by log2e; row pitch 8
    }
  } else {
    // maskbits: 8 consecutive elems/thread -> byte; 8 lanes -> one u64 word.
    int li8 = threadIdx.x & 7;
    for (size_t t = (size_t)(blk - PREP_WC) * 256 + threadIdx.x;
         t < 2097152ull; t += (size_t)PREP_MB * 256) {
      const float* mp = m + t * 8;
      f32x4 v0 = *(const f32x4*)mp;
      f32x4 v1 = *(const f32x4*)(mp + 4);
      unsigned byte =
          (v0[0] == 0.f ? 1u : 0u)  | (v0[1] == 0.f ? 2u : 0u) |
          (v0[2] == 0.f ? 4u : 0u)  | (v0[3] == 0.f ? 8u : 0u) |
          (v1[0] == 0.f ? 16u : 0u) | (v1[1] == 0.f ? 32u : 0u) |
          (v1[2] == 0.f ? 64u : 0u) | (v1[3] == 0.f ? 128u : 0u);
      u64 part = (u64)byte << (8 * li8);
      part |= __shfl_xor(part, 1);
      part |= __shfl_xor(part, 2);
      part |= __shfl_xor(part, 4);
      if (li8 == 0) {
        int w_ = (int)(t >> 3);          // word index
        int b = w_ >> 12, i = (w_ >> 3) & 511, jw = w_ & 7;
        bits[(((size_t)b * 8 + jw) << 9) + i] = part;
      }
    }
  }
}

// ---------------- k2: mid (qkv || bias_expand) ------------------------------
#define MID_QKV  1024
#define MID_BIAS 342
#define MID_GRID (MID_QKV + MID_BIAS)   // 1366

__global__ __launch_bounds__(192) void mid_kernel(
    const float* __restrict__ x,       // (32768,192) fp32
    const __bf16* __restrict__ wbf,    // (576,192) bf16
    const float* __restrict__ qb,      // (192)
    const float* __restrict__ vb,      // (192)
    __bf16* __restrict__ Qo,           // (64*6,512,32)
    __bf16* __restrict__ Ko,           // (64*6,512,32)
    __bf16* __restrict__ Vt,           // (64*6,32,512)
    const int* __restrict__ relidx,    // (512,512)
    const float* __restrict__ tab6,    // (3375,8) padded
    _Float16* __restrict__ biasH)      // (6,512,512) fp16, PERMUTED, *LOG2E
{
  __shared__ __bf16 tile[2][32][72];   // per-wave private transpose staging
  if (blockIdx.x >= MID_QKV) {
    // ---- bias_expand x4: 4 consecutive output p (same i) per thread.
    // p = jblk*64 + g*16 + kf*4 + t  <-  j = jblk*64 + kf*16 + g*4 + t;
    // aligned 4-groups map to aligned 4-groups -> one int4 relidx load.
    for (int q4 = (blockIdx.x - MID_QKV) * 192 + threadIdx.x; q4 < 65536;
         q4 += MID_BIAS * 192) {
      int ij = q4 * 4;
      int i = ij >> 9, p = ij & 511;
      int jblk = p >> 6, g = (p >> 4) & 3, kf = (p >> 2) & 3;
      int j = (jblk << 6) + kf * 16 + g * 4;
      int4v idx4 = *(const int4v*)(relidx + (i << 9) + j);
      float val[6][4];
#pragma unroll
      for (int u = 0; u < 4; ++u) {
        f32x4 lo = *(const f32x4*)(tab6 + (size_t)idx4[u] * 8);
        f32x4 hi = *(const f32x4*)(tab6 + (size_t)idx4[u] * 8 + 4);
        val[0][u] = lo[0]; val[1][u] = lo[1]; val[2][u] = lo[2];
        val[3][u] = lo[3]; val[4][u] = hi[0]; val[5][u] = hi[1];
      }
#pragma unroll
      for (int t6 = 0; t6 < 6; ++t6) {
        f16x4 o = {(_Float16)val[t6][0], (_Float16)val[t6][1],
                   (_Float16)val[t6][2], (_Float16)val[t6][3]};
        *(f16x4*)(biasH + (size_t)t6 * 262144 + ij) = o;
      }
    }
    return;
  }
  // ---- qkv
  const float CQ = 0.17677669529663687f * LOG2E;  // 1/sqrt(32) * log2e
  int lane = threadIdx.x & 63, wave = threadIdx.x >> 6;
  int g = lane >> 4, li = lane & 15;
  int rowbase = blockIdx.x * 32;
  int b = rowbase >> 9, nbase = rowbase & 511;

  bf16x8 a[2][6];
#pragma unroll
  for (int mm = 0; mm < 2; ++mm)
#pragma unroll
    for (int k = 0; k < 6; ++k) {
      const float* xp = x + (size_t)(rowbase + mm * 16 + li) * 192 + k * 32 + 8 * g;
      f32x4 x0 = *(const f32x4*)xp;
      f32x4 x1 = *(const f32x4*)(xp + 4);
      a[mm][k] = cvt2_bf16x8(x0, x1);
    }

  for (int ncl = 0; ncl < 3; ++ncl) {
    int nc = wave * 3 + ncl;           // output col chunk of 64 (region=wave)
    f32x4 acc[2][4];
#pragma unroll
    for (int n = 0; n < 4; ++n) {
      int r = nc * 64 + n * 16 + li;
      float bb = 0.0f;
      if (r < 192) bb = qb[r];
      else if (r >= 384) bb = vb[r - 384];
      f32x4 v = {bb, bb, bb, bb};
      acc[0][n] = v; acc[1][n] = v;
    }
#pragma unroll
    for (int k = 0; k < 6; ++k) {
#pragma unroll
      for (int n = 0; n < 4; ++n) {
        bf16x8 bf = *(const bf16x8*)(wbf + (size_t)(nc * 64 + n * 16 + li) * 192 + k * 32 + 8 * g);
        acc[0][n] = __builtin_amdgcn_mfma_f32_16x16x32_bf16(a[0][k], bf, acc[0][n], 0, 0, 0);
        acc[1][n] = __builtin_amdgcn_mfma_f32_16x16x32_bf16(a[1][k], bf, acc[1][n], 0, 0, 0);
      }
    }
    // Epilogue. tile[wave] written+read by the SAME wave only — no barrier.
    if (wave < 2) {
      float scale = (wave == 0) ? CQ : 1.0f;
#pragma unroll
      for (int n = 0; n < 4; ++n)
#pragma unroll
        for (int mm = 0; mm < 2; ++mm)
#pragma unroll
          for (int t = 0; t < 4; ++t)
            tile[wave][mm * 16 + 4 * g + t][n * 16 + li] = (__bf16)(acc[mm][n][t] * scale);
      int tok = lane & 31, hh = lane >> 5;
      int h = (nc * 2 + hh) % 6;
      __bf16* base = (wave == 0) ? Qo : Ko;
      __bf16* dst = base + ((size_t)(b * 6 + h) * 512 + nbase + tok) * 32;
#pragma unroll
      for (int kq = 0; kq < 4; ++kq)
        *(bf16x8*)(dst + kq * 8) = *(const bf16x8*)&tile[wave][tok][hh * 32 + kq * 8];
    } else {
#pragma unroll
      for (int n = 0; n < 4; ++n) {
        int rr = nc * 64 + n * 16 + li - 384, h = rr >> 5, d = rr & 31;
#pragma unroll
        for (int mm = 0; mm < 2; ++mm) {
          int nn = nbase + mm * 16 + 4 * g;
          bf16x4v pk;
#pragma unroll
          for (int t = 0; t < 4; ++t) pk[t] = (__bf16)acc[mm][n][t];
          *(bf16x4v*)(Vt + ((size_t)(b * 6 + h) * 32 + d) * 512 + nn) = pk;
        }
      }
    }
  }
}

// ---------------- k3: attention (64 q-rows/wave, repacked bias) -------------
__global__ __launch_bounds__(256, 3) void attn_kernel(
    const u64* __restrict__ bits,      // (64,8,512) unmasked-bit words
    const _Float16* __restrict__ biasH,// (6,512,512) fp16, PERMUTED, *LOG2E
    const __bf16* __restrict__ Qw,     // (64*6,512,32), pre-scaled
    const __bf16* __restrict__ Kw,     // (64*6,512,32)
    const __bf16* __restrict__ Vt,     // (64*6,32,512)
    float* __restrict__ out)           // (64,6,512,32) fp32
{
  // 768 blocks: XCD-chunked bijective swizzle (768 % 8 == 0, 96/XCD)
  int hw = blockIdx.x;
  int wgid = (hw & 7) * 96 + (hw >> 3);
  int qt = wgid & 1, h = (wgid >> 1) % 6, b = wgid / 12;
  int lane = threadIdx.x & 63, wave = threadIdx.x >> 6;
  int g = lane >> 4, li = lane & 15;
  int qbase = qt * 256 + wave * 64;    // 64 q-rows per wave
  int bh = b * 6 + h;
  int gsh = 4 * g;

  const __bf16* Qb = Qw + (size_t)bh * 16384;
  const __bf16* Kb = Kw + (size_t)bh * 16384;
  const __bf16* Vb = Vt + (size_t)bh * 16384;
  const _Float16* biasb = biasH + (size_t)h * 262144 + g * 16;
  const u64* bitsb = bits + (size_t)b * 4096;

  bf16x8 qfrag[4];
#pragma unroll
  for (int qf = 0; qf < 4; ++qf)
    qfrag[qf] = *(const bf16x8*)(Qb + (qbase + qf * 16 + li) * 32 + 8 * g);

  f32x4 oacc[4][2] = {};        // [qf][df]: O^T frags (col=i, row=d)
  float l_part[4] = {0.f, 0.f, 0.f, 0.f};

  for (int kb = 0; kb < 8; ++kb) {      // 64 keys per iteration
    int j64 = kb * 64;
    u64 mb[4];
#pragma unroll
    for (int qf = 0; qf < 4; ++qf)
      mb[qf] = bitsb[(kb << 9) + qbase + qf * 16 + li] >> gsh;
    bf16x8 kfr[4];
#pragma unroll
    for (int kf = 0; kf < 4; ++kf)
      kfr[kf] = *(const bf16x8*)(Kb + (j64 + kf * 16 + li) * 32 + 8 * g);
    bf16x8 vfr[2][2];
#pragma unroll
    for (int df = 0; df < 2; ++df)
#pragma unroll
      for (int c = 0; c < 2; ++c)
        vfr[df][c] = *(const bf16x8*)(Vb + (df * 16 + li) * 512 + j64 + c * 32 + 8 * g);
    // Repacked bias: lane's whole-iteration bias = 32B contiguous -> 2 loads.
    f16x8 hv8[4][2];
#pragma unroll
    for (int qf = 0; qf < 4; ++qf) {
      const _Float16* bp = biasb + (size_t)(qbase + qf * 16 + li) * 512 + j64;
      hv8[qf][0] = *(const f16x8*)(bp);       // kf0 (elems 0-3), kf1 (4-7)
      hv8[qf][1] = *(const f16x8*)(bp + 8);   // kf2, kf3
    }

#pragma unroll
    for (int c = 0; c < 2; ++c) {
      unsigned lo[4][2], hi[4][2];      // [qf][kfl]
#pragma unroll
      for (int kfl = 0; kfl < 2; ++kfl) {
        int kf = c * 2 + kfl;
        const int hsel = kf >> 1, hoff = (kf & 1) * 4;
#pragma unroll
        for (int qf = 0; qf < 4; ++qf) {
          f16x8 hb = hv8[qf][hsel];
          f32x4 ci = {(float)hb[hoff], (float)hb[hoff + 1],
                      (float)hb[hoff + 2], (float)hb[hoff + 3]};
          f32x4 s = __builtin_amdgcn_mfma_f32_16x16x32_bf16(kfr[kf], qfrag[qf], ci, 0, 0, 0);
          unsigned nib = (unsigned)(mb[qf] >> (kf * 16)) & 15u;   // const shift
          float p0 = (nib & 1u) ? __builtin_amdgcn_exp2f(s[0]) : 0.0f;
          float p1 = (nib & 2u) ? __builtin_amdgcn_exp2f(s[1]) : 0.0f;
          float p2 = (nib & 4u) ? __builtin_amdgcn_exp2f(s[2]) : 0.0f;
          float p3 = (nib & 8u) ? __builtin_amdgcn_exp2f(s[3]) : 0.0f;
          l_part[qf] += (p0 + p1) + (p2 + p3);
          lo[qf][kfl] = pack2bf(p0, p1);
          hi[qf][kfl] = pack2bf(p2, p3);
        }
      }
      // In-register P^T relayout via permlane32_swap + permlane16_swap:
      //   {W(e0e1), W(e4e5)} = swap16(swap32(lo0, lo1))
      //   {W(e2e3), W(e6e7)} = swap16(swap32(hi0, hi1))
#pragma unroll
      for (int qf = 0; qf < 4; ++qf) {
        uint2v sl = __builtin_amdgcn_permlane32_swap(lo[qf][0], lo[qf][1], 0, 0);
        uint2v wl = __builtin_amdgcn_permlane16_swap(sl.x, sl.y, 0, 0);
        uint2v sh = __builtin_amdgcn_permlane32_swap(hi[qf][0], hi[qf][1], 0, 0);
        uint2v wh = __builtin_amdgcn_permlane16_swap(sh.x, sh.y, 0, 0);
        bf16x8 pf = frag_from_words(wl.x, wh.x, wl.y, wh.y);
#pragma unroll
        for (int df = 0; df < 2; ++df)
          oacc[qf][df] = __builtin_amdgcn_mfma_f32_16x16x32_bf16(vfr[df][c], pf, oacc[qf][df], 0, 0, 0);
      }
    }
  }

  // Epilogue: finish row sums across lane-groups, normalize, store f32x4.
#pragma unroll
  for (int qf = 0; qf < 4; ++qf) {
    float l = l_part[qf];
    l += __shfl_xor(l, 16);
    l += __shfl_xor(l, 32);
    float linv = 1.0f / l;
#pragma unroll
    for (int df = 0; df < 2; ++df) {
      float* op = out + ((size_t)bh * 512 + qbase + qf * 16 + li) * 32 + df * 16 + 4 * g;
      f32x4 r = oacc[qf][df] * linv;
      *(f32x4*)op = r;
    }
  }
}

extern "C" void kernel_launch(void* const* d_in, const int* in_sizes, int n_in,
                              void* d_out, int out_size, void* d_ws, size_t ws_size,
                              hipStream_t stream) {
  const float* x    = (const float*)d_in[0];
  const float* mask = (const float*)d_in[1];
  const float* wqkv = (const float*)d_in[2];
  const float* qb   = (const float*)d_in[3];
  const float* vb   = (const float*)d_in[4];
  const float* w1   = (const float*)d_in[5];
  const float* b1   = (const float*)d_in[6];
  const float* w2   = (const float*)d_in[7];
  const float* tbl  = (const float*)d_in[8];
  const int*   ridx = (const int*)d_in[9];
  float* out = (float*)d_out;

  char* ws = (char*)d_ws;
  float*    tab6  = (float*)(ws);                         //   131,072 B (3375x8 f32)
  _Float16* biasH = (_Float16*)(ws + 131072);             // 3,145,728 B
  u64*      bits  = (u64*)(ws + 131072 + 3145728);        // 2,097,152 B
  __bf16*   wbf   = (__bf16*)(ws + 131072 + 3145728 + 2097152);  // pad 262,144
  __bf16*   Q     = (__bf16*)(ws + 131072 + 3145728 + 2097152 + 262144);
  __bf16*   K     = Q + (size_t)64 * 6 * 512 * 32;        // 12,582,912 B each
  __bf16*   Vt    = K + (size_t)64 * 6 * 512 * 32;
  // total ws use: ~43.4 MB

  prep_kernel<<<PREP_GRID, 256, 0, stream>>>(wqkv, wbf, tbl, w1, b1, w2, tab6,
                                             mask, bits);
  mid_kernel<<<MID_GRID, 192, 0, stream>>>(x, wbf, qb, vb, Q, K, Vt,
                                           ridx, tab6, biasH);
  attn_kernel<<<768, 256, 0, stream>>>(bits, biasH, Q, K, Vt, out);
}